// Round 5
// baseline (552.023 us; speedup 1.0000x reference)
//
#include <hip/hip_runtime.h>
#include <hip/hip_bf16.h>
#include <stdint.h>

#define NN 16384
#define BM 32
#define BK 64
#define NSTEPS (NN / BK)   // 256

typedef __attribute__((ext_vector_type(8))) short bf16x8;   // MFMA A/B frag: 8 bf16
typedef __attribute__((ext_vector_type(4))) float f32x4;
typedef __attribute__((ext_vector_type(4))) unsigned short u16x4;
typedef __attribute__((ext_vector_type(8))) unsigned short u16x8;
typedef __attribute__((ext_vector_type(4))) unsigned int u32x4;

__device__ __forceinline__ unsigned short f2bf(float f) {
    uint32_t u = __builtin_bit_cast(uint32_t, f);
    u += 0x7fffu + ((u >> 16) & 1u);   // RNE; inputs are finite
    return (unsigned short)(u >> 16);
}

// Tiled transpose: neighT[c][r] = bf16(neigh[r][c]). Coalesced reads AND writes.
__global__ __launch_bounds__(256) void prep_transpose(const float* __restrict__ src,
                                                      unsigned short* __restrict__ dstT) {
    __shared__ unsigned short tl[128][66];   // [c][r], pad to break bank alias
    const int t = threadIdx.x;
    const int r0 = blockIdx.x * 64;
#pragma unroll
    for (int i = 0; i < 8; ++i) {
        int idx = i * 256 + t;
        int r = idx >> 5;            // 0..63
        int s = idx & 31;            // f32x4 slot within 128-col row
        f32x4 v = *(const f32x4*)(src + (size_t)(r0 + r) * 128 + s * 4);
#pragma unroll
        for (int j = 0; j < 4; ++j) tl[s * 4 + j][r] = f2bf(v[j]);
    }
    __syncthreads();
    const int c = t >> 1;
    const int half = t & 1;
#pragma unroll
    for (int j = 0; j < 4; ++j) {
        u16x8 p;
#pragma unroll
        for (int e = 0; e < 8; ++e) p[e] = tl[c][half * 32 + j * 8 + e];
        *(u16x8*)(dstT + (size_t)c * NN + r0 + half * 32 + j * 8) = p;
    }
}

#define MFMA16(a, b, c) __builtin_amdgcn_mfma_f32_16x16x32_bf16(a, b, c, 0, 0, 0)

// Raw barrier: make ds_writes visible, do NOT drain vmcnt (global loads stay in flight).
#define BARRIER() do {                                          \
    __builtin_amdgcn_sched_barrier(0);                          \
    asm volatile("s_waitcnt lgkmcnt(0)" ::: "memory");          \
    __builtin_amdgcn_s_barrier();                               \
    __builtin_amdgcn_sched_barrier(0);                          \
} while (0)

__global__ __launch_bounds__(256, 4) void sage_fused(
    const float* __restrict__ adj,
    const float* __restrict__ feat,
    const unsigned short* __restrict__ neighT,
    const float* __restrict__ W,
    float* __restrict__ out)
{
    // LDS 16.25 KB -> 4 blocks/CU. Main: A dbuf 8 KB. Epilogue: d_lds 16 KB aliases it.
    __shared__ __align__(16) char smem[16512];
    char* aL = smem;                        // [2][BM*BK] bf16, swizzled (4 KB per buf)
    char* dL = smem;                        // epilogue [BM*256] bf16, swizzled (alias)
    float* degp = (float*)(smem + 16384);   // [BM]

    const int t = threadIdx.x;
    const int lane = t & 63;
    const int wv = t >> 6;        // wave 0..3
    const int mt = wv >> 1;       // wave row 0..1 (16 rows each)
    const int nt = wv & 1;        // wave col 0..1 (64 cols each)
    const size_t row0 = (size_t)blockIdx.x * BM;

    // A staging: i=0..1: row = 16*i + (t>>4), float4-slot = t&15
    const int ar0 = t >> 4;
    const int acs = (t & 15) * 4;
    const float* aG = adj + (row0 + ar0) * (size_t)NN + acs;

    int awb[2];
#pragma unroll
    for (int i = 0; i < 2; ++i) {
        int ar = ar0 + 16 * i;
        awb[i] = ((ar * (BK * 2)) + acs * 2) ^ ((ar & 7) << 4);
    }

    // B direct-from-global fragment base: lane reads neighT[col][k..k+8]
    const unsigned short* bG = neighT + (size_t)(nt * 64 + (lane & 15)) * NN + ((lane >> 4) * 8);

    f32x4 acc[4];
#pragma unroll
    for (int j = 0; j < 4; ++j) acc[j] = (f32x4){0.f, 0.f, 0.f, 0.f};

    float dsum[2] = {0.f, 0.f};

    f32x4 arA[2];
    u32x4 brF[8], brG[8];

#define ISSUE_A(KOFF) do {                                                    \
    _Pragma("unroll")                                                         \
    for (int i = 0; i < 2; ++i)                                               \
        arA[i] = __builtin_nontemporal_load(                                  \
            (const f32x4*)(aG + (size_t)(16 * i) * NN + (KOFF)));             \
} while (0)

#define ISSUE_B(BR, KT) do {                                                  \
    _Pragma("unroll")                                                         \
    for (int ns = 0; ns < 4; ++ns)                                            \
        _Pragma("unroll")                                                     \
        for (int ks = 0; ks < 2; ++ks)                                        \
            BR[ns * 2 + ks] = *(const u32x4*)(bG + (size_t)ns * 16 * NN +     \
                                              (size_t)(KT) * 64 + ks * 32);   \
} while (0)

#define STAGE_A(BUF) do {                                                     \
    char* aW = aL + (BUF) * (BM * BK * 2);                                    \
    _Pragma("unroll")                                                         \
    for (int i = 0; i < 2; ++i) {                                             \
        f32x4 v = arA[i];                                                     \
        dsum[i] += (v[0] + v[1]) + (v[2] + v[3]);                             \
        u16x4 p; p.x = f2bf(v[0]); p.y = f2bf(v[1]);                          \
        p.z = f2bf(v[2]); p.w = f2bf(v[3]);                                   \
        *(u16x4*)(aW + awb[i]) = p;                                           \
    }                                                                         \
} while (0)

#define COMPUTE(BUF, BR) do {                                                 \
    const char* aB = aL + (BUF) * (BM * BK * 2);                              \
    _Pragma("unroll")                                                         \
    for (int ks = 0; ks < 2; ++ks) {                                          \
        bf16x8 af;                                                            \
        {                                                                     \
            int r = mt * 16 + (lane & 15);                                    \
            int off = (r * (BK * 2) + ks * 64 + (lane >> 4) * 16)             \
                      ^ ((r & 7) << 4);                                       \
            af = *(const bf16x8*)(aB + off);                                  \
        }                                                                     \
        _Pragma("unroll")                                                     \
        for (int ns = 0; ns < 4; ++ns)                                        \
            acc[ns] = MFMA16(af, __builtin_bit_cast(bf16x8, BR[ns * 2 + ks]), \
                             acc[ns]);                                        \
    }                                                                         \
} while (0)

    // prologue: B0 in regs; A0 load+stage (one vmcnt stall, once); A1,B1 in flight
    ISSUE_B(brF, 0);
    ISSUE_A(0);
    STAGE_A(0);
    ISSUE_A(BK);
    ISSUE_B(brG, 1);
    BARRIER();

    for (int kt = 0; kt < NSTEPS; kt += 2) {
        // even: buf0 = tile kt; brF = B(kt); in flight: A(kt+1), B(kt+1)
        COMPUTE(0, brF);
        if (kt + 2 < NSTEPS) ISSUE_B(brF, kt + 2);
        STAGE_A(1);                                   // waits A(kt+1) (counted vmcnt)
        if (kt + 2 < NSTEPS) ISSUE_A((size_t)(kt + 2) * BK);
        BARRIER();
        // odd: buf1 = tile kt+1; brG = B(kt+1); in flight: A(kt+2), B(kt+2)
        COMPUTE(1, brG);
        if (kt + 3 < NSTEPS) ISSUE_B(brG, kt + 3);
        if (kt + 2 < NSTEPS) STAGE_A(0);
        if (kt + 3 < NSTEPS) ISSUE_A((size_t)(kt + 3) * BK);
        BARRIER();
    }

    // ---- degree: 16-lane shfl tree (threads 16r..16r+15 share row r) ----
#pragma unroll
    for (int m = 1; m < 16; m <<= 1) {
        dsum[0] += __shfl_xor(dsum[0], m, 64);
        dsum[1] += __shfl_xor(dsum[1], m, 64);
    }
    if ((t & 15) == 0) {
        degp[ar0] = dsum[0];
        degp[ar0 + 16] = dsum[1];
    }
    __syncthreads();   // full drain; also fences before d_lds aliases a_lds

    // ---- h = S/deg -> d_lds cols [128,256) ----
#pragma unroll
    for (int ns = 0; ns < 4; ++ns)
#pragma unroll
        for (int j = 0; j < 4; ++j) {
            int r = mt * 16 + (lane >> 4) * 4 + j;
            int c = 128 + nt * 64 + ns * 16 + (lane & 15);
            float v = acc[ns][j] / (degp[r] + 1.0f);
            int off = (r * 512 + c * 2) ^ ((r & 7) << 4);
            *(unsigned short*)(dL + off) = f2bf(v);
        }

    // ---- features -> d_lds cols [0,128) ----
#pragma unroll
    for (int i = 0; i < 4; ++i) {
        int idx = i * 256 + t;
        int r = idx >> 5;          // 32 float4-slots per 128-f32 row
        int s = idx & 31;
        f32x4 v = *(const f32x4*)(feat + (row0 + r) * 128 + s * 4);
        u16x4 p; p.x = f2bf(v[0]); p.y = f2bf(v[1]); p.z = f2bf(v[2]); p.w = f2bf(v[3]);
        int off = (r * 512 + s * 8) ^ ((r & 7) << 4);
        *(u16x4*)(dL + off) = p;
    }
    __syncthreads();

    // ---- out = data(32x256) @ W^T via MFMA, K=256; W frags straight from global f32 ----
    f32x4 acc2[4];
#pragma unroll
    for (int j = 0; j < 4; ++j) acc2[j] = (f32x4){0.f, 0.f, 0.f, 0.f};

#pragma unroll
    for (int ks = 0; ks < 8; ++ks) {
        bf16x8 af, bfr[4];
        {
            int r = mt * 16 + (lane & 15);
            int off = (r * 512 + ks * 64 + (lane >> 4) * 16) ^ ((r & 7) << 4);
            af = *(const bf16x8*)(dL + off);
        }
#pragma unroll
        for (int ns = 0; ns < 4; ++ns) {
            int c = nt * 64 + ns * 16 + (lane & 15);
            int k0 = ks * 32 + (lane >> 4) * 8;
            f32x4 w0 = *(const f32x4*)(W + (size_t)c * 256 + k0);
            f32x4 w1 = *(const f32x4*)(W + (size_t)c * 256 + k0 + 4);
            u16x8 p;
            p[0] = f2bf(w0[0]); p[1] = f2bf(w0[1]); p[2] = f2bf(w0[2]); p[3] = f2bf(w0[3]);
            p[4] = f2bf(w1[0]); p[5] = f2bf(w1[1]); p[6] = f2bf(w1[2]); p[7] = f2bf(w1[3]);
            bfr[ns] = __builtin_bit_cast(bf16x8, p);
        }
#pragma unroll
        for (int ns = 0; ns < 4; ++ns)
            acc2[ns] = MFMA16(af, bfr[ns], acc2[ns]);
    }

    // ---- store f32 ----
#pragma unroll
    for (int ns = 0; ns < 4; ++ns)
#pragma unroll
        for (int j = 0; j < 4; ++j) {
            int r = mt * 16 + (lane >> 4) * 4 + j;
            int c = nt * 64 + ns * 16 + (lane & 15);
            out[(row0 + r) * 128 + c] = acc2[ns][j];
        }
}

extern "C" void kernel_launch(void* const* d_in, const int* in_sizes, int n_in,
                              void* d_out, int out_size, void* d_ws, size_t ws_size,
                              hipStream_t stream) {
    const float* adj = (const float*)d_in[0];
    const float* feat = (const float*)d_in[1];
    const float* neigh = (const float*)d_in[2];
    const float* W = (const float*)d_in[3];
    float* out = (float*)d_out;
    unsigned short* neighT = (unsigned short*)d_ws;   // 128 x 16384 bf16 = 4 MiB

    prep_transpose<<<NN / 64, 256, 0, stream>>>(neigh, neighT);
    sage_fused<<<NN / BM, 256, 0, stream>>>(adj, feat, neighT, W, out);
}

// Round 6
// 502.839 us; speedup vs baseline: 1.0978x; 1.0978x over previous
//
#include <hip/hip_runtime.h>
#include <hip/hip_bf16.h>
#include <stdint.h>

#define NN 16384
#define BM 32
#define BK 64
#define NSTEPS (NN / BK)   // 256

typedef __attribute__((ext_vector_type(8))) short bf16x8;   // MFMA A/B frag: 8 bf16
typedef __attribute__((ext_vector_type(4))) float f32x4;
typedef __attribute__((ext_vector_type(4))) unsigned short u16x4;
typedef __attribute__((ext_vector_type(8))) unsigned short u16x8;
typedef __attribute__((ext_vector_type(4))) unsigned int u32x4;

__device__ __forceinline__ unsigned short f2bf(float f) {
    uint32_t u = __builtin_bit_cast(uint32_t, f);
    u += 0x7fffu + ((u >> 16) & 1u);   // RNE; inputs are finite
    return (unsigned short)(u >> 16);
}

// Tiled transpose: neighT[c][r] = bf16(neigh[r][c]). Coalesced reads AND writes.
__global__ __launch_bounds__(256) void prep_transpose(const float* __restrict__ src,
                                                      unsigned short* __restrict__ dstT) {
    __shared__ unsigned short tl[128][66];   // [c][r], pad to break bank alias
    const int t = threadIdx.x;
    const int r0 = blockIdx.x * 64;
#pragma unroll
    for (int i = 0; i < 8; ++i) {
        int idx = i * 256 + t;
        int r = idx >> 5;            // 0..63
        int s = idx & 31;            // f32x4 slot within 128-col row
        f32x4 v = *(const f32x4*)(src + (size_t)(r0 + r) * 128 + s * 4);
#pragma unroll
        for (int j = 0; j < 4; ++j) tl[s * 4 + j][r] = f2bf(v[j]);
    }
    __syncthreads();
    const int c = t >> 1;
    const int half = t & 1;
#pragma unroll
    for (int j = 0; j < 4; ++j) {
        u16x8 p;
#pragma unroll
        for (int e = 0; e < 8; ++e) p[e] = tl[c][half * 32 + j * 8 + e];
        *(u16x8*)(dstT + (size_t)c * NN + r0 + half * 32 + j * 8) = p;
    }
}

#define MFMA16(a, b, c) __builtin_amdgcn_mfma_f32_16x16x32_bf16(a, b, c, 0, 0, 0)

// Raw barrier: make ds_writes visible (lgkmcnt only), do NOT drain vmcnt.
// Single trailing sched_barrier keeps later LDS reads from hoisting above s_barrier.
#define BARRIER() do {                                          \
    asm volatile("s_waitcnt lgkmcnt(0)" ::: "memory");          \
    __builtin_amdgcn_s_barrier();                               \
    __builtin_amdgcn_sched_barrier(0);                          \
} while (0)

__global__ __launch_bounds__(256, 2) void sage_fused(
    const float* __restrict__ adj,
    const float* __restrict__ feat,
    const unsigned short* __restrict__ neighT,
    const float* __restrict__ W,
    float* __restrict__ out)
{
    // LDS 16.25 KB. Main: A dbuf 8 KB. Epilogue: d_lds 16 KB aliases it.
    __shared__ __align__(16) char smem[16512];
    char* aL = smem;                        // [2][BM*BK] bf16, swizzled (4 KB per buf)
    char* dL = smem;                        // epilogue [BM*256] bf16, swizzled (alias)
    float* degp = (float*)(smem + 16384);   // [BM]

    const int t = threadIdx.x;
    const int lane = t & 63;
    const int wv = t >> 6;        // wave 0..3
    const int mt = wv >> 1;       // wave row 0..1 (16 rows each)
    const int nt = wv & 1;        // wave col 0..1 (64 cols each)
    const size_t row0 = (size_t)blockIdx.x * BM;

    // A staging: i=0..1: row = 16*i + (t>>4), float4-slot = t&15
    const int ar0 = t >> 4;
    const int acs = (t & 15) * 4;
    const float* aG = adj + (row0 + ar0) * (size_t)NN + acs;

    int awb[2];
#pragma unroll
    for (int i = 0; i < 2; ++i) {
        int ar = ar0 + 16 * i;
        awb[i] = ((ar * (BK * 2)) + acs * 2) ^ ((ar & 7) << 4);
    }

    // B direct-from-global fragment base: lane reads neighT[col][k..k+8]
    const unsigned short* bG = neighT + (size_t)(nt * 64 + (lane & 15)) * NN + ((lane >> 4) * 8);

    f32x4 acc[4];
#pragma unroll
    for (int j = 0; j < 4; ++j) acc[j] = (f32x4){0.f, 0.f, 0.f, 0.f};

    float dsum[2] = {0.f, 0.f};

    f32x4 arA[2], arB[2];
    u32x4 brF[8], brG[8];

#define ISSUE_A(AR, KOFF) do {                                                \
    _Pragma("unroll")                                                         \
    for (int i = 0; i < 2; ++i)                                               \
        AR[i] = __builtin_nontemporal_load(                                   \
            (const f32x4*)(aG + (size_t)(16 * i) * NN + (KOFF)));             \
} while (0)

#define ISSUE_B(BR, KT) do {                                                  \
    _Pragma("unroll")                                                         \
    for (int ns = 0; ns < 4; ++ns)                                            \
        _Pragma("unroll")                                                     \
        for (int ks = 0; ks < 2; ++ks)                                        \
            BR[ns * 2 + ks] = *(const u32x4*)(bG + (size_t)ns * 16 * NN +     \
                                              (size_t)(KT) * 64 + ks * 32);   \
} while (0)

#define STAGE_A(AR, BUF) do {                                                 \
    char* aW = aL + (BUF) * (BM * BK * 2);                                    \
    _Pragma("unroll")                                                         \
    for (int i = 0; i < 2; ++i) {                                             \
        f32x4 v = AR[i];                                                      \
        dsum[i] += (v[0] + v[1]) + (v[2] + v[3]);                             \
        u16x4 p; p.x = f2bf(v[0]); p.y = f2bf(v[1]);                          \
        p.z = f2bf(v[2]); p.w = f2bf(v[3]);                                   \
        *(u16x4*)(aW + awb[i]) = p;                                           \
    }                                                                         \
} while (0)

#define COMPUTE(BUF, BR) do {                                                 \
    const char* aB = aL + (BUF) * (BM * BK * 2);                              \
    _Pragma("unroll")                                                         \
    for (int ks = 0; ks < 2; ++ks) {                                          \
        bf16x8 af;                                                            \
        {                                                                     \
            int r = mt * 16 + (lane & 15);                                    \
            int off = (r * (BK * 2) + ks * 64 + (lane >> 4) * 16)             \
                      ^ ((r & 7) << 4);                                       \
            af = *(const bf16x8*)(aB + off);                                  \
        }                                                                     \
        _Pragma("unroll")                                                     \
        for (int ns = 0; ns < 4; ++ns)                                        \
            acc[ns] = MFMA16(af, __builtin_bit_cast(bf16x8, BR[ns * 2 + ks]), \
                             acc[ns]);                                        \
    }                                                                         \
} while (0)

    // prologue: stage tile 0; tiles 1 in flight (arB, brG)
    ISSUE_B(brF, 0);
    ISSUE_A(arA, 0);
    STAGE_A(arA, 0);
    ISSUE_B(brG, 1);
    ISSUE_A(arB, BK);
    BARRIER();

    // invariant at even top: buf0=A(kt) staged, brF=B(kt) arrived-or-waited;
    // in flight: arB=A(kt+1), brG=B(kt+1)
    for (int kt = 0; kt < NSTEPS; kt += 2) {
        COMPUTE(0, brF);
        if (kt + 2 < NSTEPS) {
            ISSUE_B(brF, kt + 2);
            ISSUE_A(arA, (size_t)(kt + 2) * BK);
        }
        STAGE_A(arB, 1);                 // tile kt+1 (always < NSTEPS)
        BARRIER();

        COMPUTE(1, brG);
        if (kt + 3 < NSTEPS) {
            ISSUE_B(brG, kt + 3);
            ISSUE_A(arB, (size_t)(kt + 3) * BK);
        }
        if (kt + 2 < NSTEPS) STAGE_A(arA, 0);
        BARRIER();
    }

    // ---- degree: 16-lane shfl tree (threads 16r..16r+15 share row r) ----
#pragma unroll
    for (int m = 1; m < 16; m <<= 1) {
        dsum[0] += __shfl_xor(dsum[0], m, 64);
        dsum[1] += __shfl_xor(dsum[1], m, 64);
    }
    if ((t & 15) == 0) {
        degp[ar0] = dsum[0];
        degp[ar0 + 16] = dsum[1];
    }
    __syncthreads();   // full drain; also fences before d_lds aliases a_lds

    // ---- h = S/deg -> d_lds cols [128,256) ----
#pragma unroll
    for (int ns = 0; ns < 4; ++ns)
#pragma unroll
        for (int j = 0; j < 4; ++j) {
            int r = mt * 16 + (lane >> 4) * 4 + j;
            int c = 128 + nt * 64 + ns * 16 + (lane & 15);
            float v = acc[ns][j] / (degp[r] + 1.0f);
            int off = (r * 512 + c * 2) ^ ((r & 7) << 4);
            *(unsigned short*)(dL + off) = f2bf(v);
        }

    // ---- features -> d_lds cols [0,128) ----
#pragma unroll
    for (int i = 0; i < 4; ++i) {
        int idx = i * 256 + t;
        int r = idx >> 5;          // 32 float4-slots per 128-f32 row
        int s = idx & 31;
        f32x4 v = *(const f32x4*)(feat + (row0 + r) * 128 + s * 4);
        u16x4 p; p.x = f2bf(v[0]); p.y = f2bf(v[1]); p.z = f2bf(v[2]); p.w = f2bf(v[3]);
        int off = (r * 512 + s * 8) ^ ((r & 7) << 4);
        *(u16x4*)(dL + off) = p;
    }
    __syncthreads();

    // ---- out = data(32x256) @ W^T via MFMA, K=256; W frags straight from global f32 ----
    f32x4 acc2[4];
#pragma unroll
    for (int j = 0; j < 4; ++j) acc2[j] = (f32x4){0.f, 0.f, 0.f, 0.f};

#pragma unroll
    for (int ks = 0; ks < 8; ++ks) {
        bf16x8 af, bfr[4];
        {
            int r = mt * 16 + (lane & 15);
            int off = (r * 512 + ks * 64 + (lane >> 4) * 16) ^ ((r & 7) << 4);
            af = *(const bf16x8*)(dL + off);
        }
#pragma unroll
        for (int ns = 0; ns < 4; ++ns) {
            int c = nt * 64 + ns * 16 + (lane & 15);
            int k0 = ks * 32 + (lane >> 4) * 8;
            f32x4 w0 = *(const f32x4*)(W + (size_t)c * 256 + k0);
            f32x4 w1 = *(const f32x4*)(W + (size_t)c * 256 + k0 + 4);
            u16x8 p;
            p[0] = f2bf(w0[0]); p[1] = f2bf(w0[1]); p[2] = f2bf(w0[2]); p[3] = f2bf(w0[3]);
            p[4] = f2bf(w1[0]); p[5] = f2bf(w1[1]); p[6] = f2bf(w1[2]); p[7] = f2bf(w1[3]);
            bfr[ns] = __builtin_bit_cast(bf16x8, p);
        }
#pragma unroll
        for (int ns = 0; ns < 4; ++ns)
            acc2[ns] = MFMA16(af, bfr[ns], acc2[ns]);
    }

    // ---- store f32 ----
#pragma unroll
    for (int ns = 0; ns < 4; ++ns)
#pragma unroll
        for (int j = 0; j < 4; ++j) {
            int r = mt * 16 + (lane >> 4) * 4 + j;
            int c = nt * 64 + ns * 16 + (lane & 15);
            out[(row0 + r) * 128 + c] = acc2[ns][j];
        }
}

extern "C" void kernel_launch(void* const* d_in, const int* in_sizes, int n_in,
                              void* d_out, int out_size, void* d_ws, size_t ws_size,
                              hipStream_t stream) {
    const float* adj = (const float*)d_in[0];
    const float* feat = (const float*)d_in[1];
    const float* neigh = (const float*)d_in[2];
    const float* W = (const float*)d_in[3];
    float* out = (float*)d_out;
    unsigned short* neighT = (unsigned short*)d_ws;   // 128 x 16384 bf16 = 4 MiB

    prep_transpose<<<NN / 64, 256, 0, stream>>>(neigh, neighT);
    sage_fused<<<NN / BM, 256, 0, stream>>>(adj, feat, neighT, W, out);
}

// Round 7
// 271.602 us; speedup vs baseline: 2.0325x; 1.8514x over previous
//
#include <hip/hip_runtime.h>
#include <hip/hip_bf16.h>
#include <stdint.h>

#define NN 16384
#define BM 32
#define BK 64
#define NSTEPS (NN / BK)   // 256

typedef __attribute__((ext_vector_type(8))) short bf16x8;   // MFMA A/B frag: 8 bf16
typedef __attribute__((ext_vector_type(4))) float f32x4;
typedef __attribute__((ext_vector_type(4))) unsigned short u16x4;
typedef __attribute__((ext_vector_type(8))) unsigned short u16x8;
typedef __attribute__((ext_vector_type(4))) unsigned int u32x4;

__device__ __forceinline__ unsigned short f2bf(float f) {
    uint32_t u = __builtin_bit_cast(uint32_t, f);
    u += 0x7fffu + ((u >> 16) & 1u);   // RNE; inputs are finite
    return (unsigned short)(u >> 16);
}

// Tiled transpose: neighT[c][r] = bf16(neigh[r][c]). Coalesced reads AND writes.
__global__ __launch_bounds__(256) void prep_transpose(const float* __restrict__ src,
                                                      unsigned short* __restrict__ dstT) {
    __shared__ unsigned short tl[128][66];   // [c][r], pad to break bank alias
    const int t = threadIdx.x;
    const int r0 = blockIdx.x * 64;
#pragma unroll
    for (int i = 0; i < 8; ++i) {
        int idx = i * 256 + t;
        int r = idx >> 5;            // 0..63
        int s = idx & 31;            // f32x4 slot within 128-col row
        f32x4 v = *(const f32x4*)(src + (size_t)(r0 + r) * 128 + s * 4);
#pragma unroll
        for (int j = 0; j < 4; ++j) tl[s * 4 + j][r] = f2bf(v[j]);
    }
    __syncthreads();
    const int c = t >> 1;
    const int half = t & 1;
#pragma unroll
    for (int j = 0; j < 4; ++j) {
        u16x8 p;
#pragma unroll
        for (int e = 0; e < 8; ++e) p[e] = tl[c][half * 32 + j * 8 + e];
        *(u16x8*)(dstT + (size_t)c * NN + r0 + half * 32 + j * 8) = p;
    }
}

#define MFMA16(a, b, c) __builtin_amdgcn_mfma_f32_16x16x32_bf16(a, b, c, 0, 0, 0)

__global__ __launch_bounds__(256, 2) void sage_fused(
    const float* __restrict__ adj,
    const float* __restrict__ feat,
    const unsigned short* __restrict__ neighT,
    const float* __restrict__ W,
    float* __restrict__ out)
{
    // LDS 40.1 KB (a 8K + b 32K; epilogue d_lds 16K aliases the front; degp tail)
    __shared__ __align__(16) char smem[41088];
    char* aL = smem;                        // [2][BM*BK] bf16, swizzled
    char* bL = smem + 8192;                 // [2][128*BK] bf16, swizzled
    char* dL = smem;                        // epilogue [BM*256] bf16, swizzled (alias)
    float* degp = (float*)(smem + 40960);   // [BM]

    const int t = threadIdx.x;
    const int lane = t & 63;
    const int wv = t >> 6;        // wave 0..3
    const int mt = wv >> 1;       // wave row 0..1 (16 rows each)
    const int nt = wv & 1;        // wave col 0..1 (64 cols each)
    const size_t row0 = (size_t)blockIdx.x * BM;

    if (t < BM) degp[t] = 0.f;

    // A (f32): i=0..1: row = 16*i + (t>>4), float4-slot = t&15
    const int ar0 = t >> 4;
    const int acs = (t & 15) * 4;
    // B (bf16): i=0..3: row(c) = 32*i + (t>>3), 16B-slot = t&7
    const int br0 = t >> 3;
    const int bcs = (t & 7) * 8;

    const float* aG = adj + (row0 + ar0) * (size_t)NN + acs;
    const unsigned short* bG = neighT + (size_t)br0 * NN + bcs;

    int awb[2], bwb[4];
#pragma unroll
    for (int i = 0; i < 2; ++i) {
        int ar = ar0 + 16 * i;
        awb[i] = ((ar * (BK * 2)) + acs * 2) ^ ((ar & 7) << 4);
    }
#pragma unroll
    for (int i = 0; i < 4; ++i) {
        int br = br0 + 32 * i;
        bwb[i] = ((br * (BK * 2)) + bcs * 2) ^ ((br & 7) << 4);
    }

    f32x4 acc[4];
#pragma unroll
    for (int j = 0; j < 4; ++j) acc[j] = (f32x4){0.f, 0.f, 0.f, 0.f};

    float dsum[2] = {0.f, 0.f};

    f32x4 ar_[2];
    u32x4 br_[4];

    // prologue: load + stage tile 0 into buf 0 (one full-latency stall, once)
#pragma unroll
    for (int i = 0; i < 2; ++i)
        ar_[i] = __builtin_nontemporal_load((const f32x4*)(aG + (size_t)(16 * i) * NN));
#pragma unroll
    for (int i = 0; i < 4; ++i)
        br_[i] = *(const u32x4*)(bG + (size_t)(32 * i) * NN);
#pragma unroll
    for (int i = 0; i < 2; ++i) {
        f32x4 v = ar_[i];
        dsum[i] += (v[0] + v[1]) + (v[2] + v[3]);
        u16x4 p; p.x = f2bf(v[0]); p.y = f2bf(v[1]); p.z = f2bf(v[2]); p.w = f2bf(v[3]);
        *(u16x4*)(aL + awb[i]) = p;
    }
#pragma unroll
    for (int i = 0; i < 4; ++i)
        *(u32x4*)(bL + bwb[i]) = br_[i];
    __syncthreads();

    int cur = 0;
    // steady state: barrier -> ISSUE(kt+1) -> COMPUTE(kt) -> STAGE(kt+1) -> barrier
    // Loads are issued right AFTER the barrier so COMPUTE covers their latency;
    // the vmcnt(0) in the next __syncthreads hits already-consumed loads.
    for (int kt = 0; kt < NSTEPS; ++kt) {
        const bool pf = (kt + 1 < NSTEPS);
        if (pf) {
            const size_t koff = (size_t)(kt + 1) * BK;
#pragma unroll
            for (int i = 0; i < 2; ++i)
                ar_[i] = __builtin_nontemporal_load((const f32x4*)(aG + (size_t)(16 * i) * NN + koff));
#pragma unroll
            for (int i = 0; i < 4; ++i)
                br_[i] = *(const u32x4*)(bG + (size_t)(32 * i) * NN + koff);
        }
        {
            const char* aB = aL + cur * (BM * BK * 2);
            const char* bB = bL + cur * (128 * BK * 2);
#pragma unroll
            for (int ks = 0; ks < 2; ++ks) {
                bf16x8 af, bfr[4];
                {
                    int r = mt * 16 + (lane & 15);
                    int off = (r * (BK * 2) + ks * 64 + (lane >> 4) * 16) ^ ((r & 7) << 4);
                    af = *(const bf16x8*)(aB + off);
                }
#pragma unroll
                for (int ns = 0; ns < 4; ++ns) {
                    int c = nt * 64 + ns * 16 + (lane & 15);
                    int off = (c * (BK * 2) + ks * 64 + (lane >> 4) * 16) ^ ((c & 7) << 4);
                    bfr[ns] = *(const bf16x8*)(bB + off);
                }
#pragma unroll
                for (int ns = 0; ns < 4; ++ns)
                    acc[ns] = MFMA16(af, bfr[ns], acc[ns]);
            }
        }
        if (pf) {
            char* aW = aL + (cur ^ 1) * (BM * BK * 2);
            char* bW = bL + (cur ^ 1) * (128 * BK * 2);
#pragma unroll
            for (int i = 0; i < 2; ++i) {
                f32x4 v = ar_[i];
                dsum[i] += (v[0] + v[1]) + (v[2] + v[3]);
                u16x4 p; p.x = f2bf(v[0]); p.y = f2bf(v[1]); p.z = f2bf(v[2]); p.w = f2bf(v[3]);
                *(u16x4*)(aW + awb[i]) = p;
            }
#pragma unroll
            for (int i = 0; i < 4; ++i)
                *(u32x4*)(bW + bwb[i]) = br_[i];
        }
        __syncthreads();
        cur ^= 1;
    }

    // ---- degree reduction ----
#pragma unroll
    for (int i = 0; i < 2; ++i)
        atomicAdd(&degp[ar0 + 16 * i], dsum[i]);
    __syncthreads();   // also fences before d_lds aliases the main buffers

    // ---- h = S/deg -> d_lds cols [128,256) ----
#pragma unroll
    for (int ns = 0; ns < 4; ++ns)
#pragma unroll
        for (int j = 0; j < 4; ++j) {
            int r = mt * 16 + (lane >> 4) * 4 + j;
            int c = 128 + nt * 64 + ns * 16 + (lane & 15);
            float v = acc[ns][j] / (degp[r] + 1.0f);
            int off = (r * 512 + c * 2) ^ ((r & 7) << 4);
            *(unsigned short*)(dL + off) = f2bf(v);
        }

    // ---- features -> d_lds cols [0,128) ----
#pragma unroll
    for (int i = 0; i < 4; ++i) {
        int idx = i * 256 + t;
        int r = idx >> 5;          // 32 float4-slots per 128-f32 row
        int s = idx & 31;
        f32x4 v = *(const f32x4*)(feat + (row0 + r) * 128 + s * 4);
        u16x4 p; p.x = f2bf(v[0]); p.y = f2bf(v[1]); p.z = f2bf(v[2]); p.w = f2bf(v[3]);
        int off = (r * 512 + s * 8) ^ ((r & 7) << 4);
        *(u16x4*)(dL + off) = p;
    }
    __syncthreads();

    // ---- out = data(32x256) @ W^T via MFMA, K=256; W frags straight from global f32 ----
    f32x4 acc2[4];
#pragma unroll
    for (int j = 0; j < 4; ++j) acc2[j] = (f32x4){0.f, 0.f, 0.f, 0.f};

#pragma unroll
    for (int ks = 0; ks < 8; ++ks) {
        bf16x8 af, bfr[4];
        {
            int r = mt * 16 + (lane & 15);
            int off = (r * 512 + ks * 64 + (lane >> 4) * 16) ^ ((r & 7) << 4);
            af = *(const bf16x8*)(dL + off);
        }
#pragma unroll
        for (int ns = 0; ns < 4; ++ns) {
            int c = nt * 64 + ns * 16 + (lane & 15);
            int k0 = ks * 32 + (lane >> 4) * 8;
            f32x4 w0 = *(const f32x4*)(W + (size_t)c * 256 + k0);
            f32x4 w1 = *(const f32x4*)(W + (size_t)c * 256 + k0 + 4);
            u16x8 p;
            p[0] = f2bf(w0[0]); p[1] = f2bf(w0[1]); p[2] = f2bf(w0[2]); p[3] = f2bf(w0[3]);
            p[4] = f2bf(w1[0]); p[5] = f2bf(w1[1]); p[6] = f2bf(w1[2]); p[7] = f2bf(w1[3]);
            bfr[ns] = __builtin_bit_cast(bf16x8, p);
        }
#pragma unroll
        for (int ns = 0; ns < 4; ++ns)
            acc2[ns] = MFMA16(af, bfr[ns], acc2[ns]);
    }

    // ---- store f32 ----
#pragma unroll
    for (int ns = 0; ns < 4; ++ns)
#pragma unroll
        for (int j = 0; j < 4; ++j) {
            int r = mt * 16 + (lane >> 4) * 4 + j;
            int c = nt * 64 + ns * 16 + (lane & 15);
            out[(row0 + r) * 128 + c] = acc2[ns][j];
        }
}

extern "C" void kernel_launch(void* const* d_in, const int* in_sizes, int n_in,
                              void* d_out, int out_size, void* d_ws, size_t ws_size,
                              hipStream_t stream) {
    const float* adj = (const float*)d_in[0];
    const float* feat = (const float*)d_in[1];
    const float* neigh = (const float*)d_in[2];
    const float* W = (const float*)d_in[3];
    float* out = (float*)d_out;
    unsigned short* neighT = (unsigned short*)d_ws;   // 128 x 16384 bf16 = 4 MiB

    prep_transpose<<<NN / 64, 256, 0, stream>>>(neigh, neighT);
    sage_fused<<<NN / BM, 256, 0, stream>>>(adj, feat, neighT, W, out);
}